// Round 10
// baseline (128.535 us; speedup 1.0000x reference)
//
#include <hip/hip_runtime.h>
#include <stdint.h>

// ReconstructionDecoder, factorized, THREE kernels.
// r5: no device-scope spin barriers. r6/r7: big fusion spills/starves.
// r9 falsified "scattered W1 gather" theory: streamed prep changed nothing.
// r10 theory: the persistent ~40us prep cost is the 544 row-blocks + 3.34MB
//   Abuf round-trip (present in every 44us prep, absent from r0's 4us prep,
//   whose consumer built A in-kernel). So: NO Abuf. gemm3b builds its
//   A-fragments inline from x/t_emb/f_emb (bitwise-identical bytes); prep2
//   shrinks to Bbuf(streamed)+GKW+stats = 88 blocks.
//
// Identity: h = xt[bnt] + f[fi] (broadcast sum), W1g = g*W1:
//   LN(h)@W1 + b1 = rs*( (xt@W1g)[e] + (f@W1g)[e] - mu*G[e] ) + K[e]
//   G[e] = sum_k g_k W1[k,e], K[e] = b1[e] + sum_k b_k W1[k,e],
//   mu = (Sxt+Sf)/256, var = (Sxt2 + 2*(xt.f) + Sf2)/256 - mu^2.
// 3-term bf16 split GEMM (stacked K=768): A=[hi|lo|hi], B=[W1hi|W1hi|W1lo].

#define D_ 256
#define E_ 512

typedef __attribute__((ext_vector_type(8))) short short8;
typedef __attribute__((ext_vector_type(4))) float f32x4;
typedef __attribute__((ext_vector_type(2))) float f32x2;

// ---- module-scope scratch (rewritten fully every launch; d_ws untouched) ----
__device__ alignas(16) unsigned short g_Bbuf[768 * 640];   // 0.98 MB
__device__ alignas(16) float g_U[2048 * 512];              // 4 MB
__device__ alignas(16) float g_C[2048 * 128];              // 1 MB
__device__ alignas(16) float g_Vt[512 * 128];              // 256 KB
__device__ alignas(16) float g_GKW[512 * 4];
__device__ alignas(16) float g_sxt[2048];
__device__ alignas(16) float g_sqxt[2048];
__device__ alignas(16) float g_sf[128];
__device__ alignas(16) float g_sqf[128];

__device__ inline unsigned short f2bf(float f) {
  unsigned int u = __float_as_uint(f);
  u += 0x7fffu + ((u >> 16) & 1u);
  return (unsigned short)(u >> 16);
}
__device__ inline float bf2f(unsigned short h) {
  return __uint_as_float(((unsigned int)h) << 16);
}

// Build one A-fragment (8 consecutive k's) with the 3-term hi/lo selection.
// term 0: hi, term 1: lo, term 2: hi  (matches B = [W1hi | W1hi | W1lo]).
__device__ inline short8 mk_frag(float4 a0, float4 a1, int term) {
  union { unsigned short u[8]; short8 v; } fr;
  float vv[8] = {a0.x, a0.y, a0.z, a0.w, a1.x, a1.y, a1.z, a1.w};
#pragma unroll
  for (int j = 0; j < 8; ++j) {
    const unsigned short h = f2bf(vv[j]);
    fr.u[j] = (term == 1) ? f2bf(vv[j] - bf2f(h)) : h;
  }
  return fr.v;
}

// ---------------------------------------------------------------------------
// prep2 block roles (grid 88):
//   [0,48):  Bbuf fragments via LDS-staged coalesced W1/f_emb slabs (r9 code)
//   [48,56): GKW[e] = {G, K, W2[e][0], W2[e][1]}, k-split 4 waves
//   [56,88): stats: 4 waves/block x 17 rows/wave -> sxt/sqxt/sf/sqf
// ---------------------------------------------------------------------------
__global__ __launch_bounds__(256) void prep2(
    const float* __restrict__ x, const float* __restrict__ t_emb,
    const float* __restrict__ f_emb, const float* __restrict__ ln_g,
    const float* __restrict__ ln_b, const float* __restrict__ W1,
    const float* __restrict__ b1, const float* __restrict__ W2) {
  __shared__ float sW[32][264];  // 33.8 KB; 1056B rows, 16B-aligned slots
  __shared__ float sF[128][36];  // 18.0 KB; 144B rows, 16B-aligned slots
  __shared__ float sg[32];
  __shared__ float red[4][64][2];

  const int blk = blockIdx.x;
  const int tid = threadIdx.x;
  const int wv = tid >> 6;
  const int l = tid & 63;

  if (blk < 48) {
    // ---- Bbuf via LDS-staged coalesced slabs (r9-proven) ----
    const int b = blk;               // 0..47
    const int kt = b >> 1, h = b & 1;
    const int term = kt >> 3;        // 0,1: hi; 2: lo
    const int k0 = (kt & 7) * 32;
    {
      const float4* w4 = (const float4*)(W1 + (size_t)k0 * E_ + h * 256);
      for (int i = tid; i < 2048; i += 256) {
        const int kk2 = i >> 6, c4 = i & 63;
        *(float4*)&sW[kk2][c4 * 4] = w4[kk2 * (E_ / 4) + c4];
      }
      if (tid < 32) sg[tid] = ln_g[k0 + tid];
      if (h == 0) {
        const float4* f4 = (const float4*)(f_emb + k0);
        for (int i = tid; i < 1024; i += 256) {
          const int fr = i >> 3, c4 = i & 7;
          *(float4*)&sF[fr][c4 * 4] = f4[fr * (D_ / 4) + c4];
        }
      }
    }
    __syncthreads();
    for (int fi = tid; fi < 1024; fi += 256) {
      const int ct = 4 * h + (fi >> 8);
      const int rem = fi & 255;
      const int jtl = rem >> 6, ln = rem & 63;
      const int colw = (ct - 4 * h) * 64 + jtl * 16 + (ln & 15);
      const int kb = ((ln >> 4) & 3) * 8;
      union { unsigned short u[8]; short8 v; } fr8;
#pragma unroll
      for (int j = 0; j < 8; ++j) {
        const float v = sg[kb + j] * sW[kb + j][colw];
        const unsigned short hv = f2bf(v);
        fr8.u[j] = (term == 2) ? f2bf(v - bf2f(hv)) : hv;
      }
      const int gidx = ((kt * 10 + ct) * 4 + jtl) * 64 + ln;
      *(short8*)(g_Bbuf + gidx * 8) = fr8.v;
    }
    if (h == 0) {
      for (int fi = tid; fi < 512; fi += 256) {
        const int ct = 8 + (fi >> 8);
        const int rem = fi & 255;
        const int jtl = rem >> 6, ln = rem & 63;
        const int f = (ct - 8) * 64 + jtl * 16 + (ln & 15);
        const int kb = ((ln >> 4) & 3) * 8;
        union { unsigned short u[8]; short8 v; } fr8;
#pragma unroll
        for (int j = 0; j < 8; ++j) {
          const float v = sF[f][kb + j];
          const unsigned short hv = f2bf(v);
          fr8.u[j] = (term == 2) ? f2bf(v - bf2f(hv)) : hv;
        }
        const int gidx = ((kt * 10 + ct) * 4 + jtl) * 64 + ln;
        *(short8*)(g_Bbuf + gidx * 8) = fr8.v;
      }
    }
  } else if (blk < 56) {
    // ---- GKW: block owns 64 e's; wave w owns k-range [64w,64w+64) ----
    const int e = (blk - 48) * 64 + l;
    const int k0 = wv * 64;
    float G = 0.f, K = 0.f;
#pragma unroll 8
    for (int i = 0; i < 64; ++i) {
      const float wval = W1[(k0 + i) * E_ + e];
      G = fmaf(ln_g[k0 + i], wval, G);
      K = fmaf(ln_b[k0 + i], wval, K);
    }
    red[wv][l][0] = G;
    red[wv][l][1] = K;
    __syncthreads();
    if (wv == 0) {
      G = (red[0][l][0] + red[1][l][0]) + (red[2][l][0] + red[3][l][0]);
      K = (red[0][l][1] + red[1][l][1]) + (red[2][l][1] + red[3][l][1]);
      float4 o;
      o.x = G; o.y = K + b1[e];
      o.z = W2[2 * e]; o.w = W2[2 * e + 1];
      *(float4*)(g_GKW + 4 * e) = o;
    }
  } else {
    // ---- stats: wave handles 17 rows; lane owns elements 4l..4l+3 ----
    const int w0 = ((blk - 56) * 4 + wv) * 17;  // 0,17,...,2159
    for (int i = 0; i < 17; ++i) {
      const int r = w0 + i;  // < 2176
      float v0, v1, v2, v3;
      if (r < 2048) {
        const int bn = r >> 7, t = r & 127;
        const float4 xv = *(const float4*)(x + bn * D_ + 4 * l);
        const float4 tv = *(const float4*)(t_emb + t * D_ + 4 * l);
        v0 = xv.x + tv.x; v1 = xv.y + tv.y;
        v2 = xv.z + tv.z; v3 = xv.w + tv.w;
      } else {
        const float4 fv = *(const float4*)(f_emb + (r - 2048) * D_ + 4 * l);
        v0 = fv.x; v1 = fv.y; v2 = fv.z; v3 = fv.w;
      }
      float s = (v0 + v1) + (v2 + v3);
      float q = fmaf(v0, v0, fmaf(v1, v1, fmaf(v2, v2, v3 * v3)));
#pragma unroll
      for (int d = 1; d < 64; d <<= 1) {
        s += __shfl_xor(s, d);
        q += __shfl_xor(q, d);
      }
      if (l == 0) {
        if (r < 2048) { g_sxt[r] = s; g_sqxt[r] = q; }
        else          { g_sf[r - 2048] = s; g_sqf[r - 2048] = q; }
      }
    }
  }
}

// ---------------------------------------------------------------------------
// gemm3b: [2176 x 768] @ [768 x 640], 128x64 tiles, grid 17x10 = 170.
// A-fragments built INLINE from x/t_emb (rt<16) or f_emb (rt==16): per kt,
// v = x[rt*256+k] + t_emb[t*256+k] (x-row block-uniform; t-row per-lane),
// then hi/lo per 3-term split — bytes identical to the old Abuf path.
// B fragments MFMA-ordered in g_Bbuf (L2-resident), straight global->VGPR.
// No LDS, no barriers. Output: rt<16,ct<8 -> U; ct>=8 -> C; rt==16 -> Vt.
// ---------------------------------------------------------------------------
__global__ __launch_bounds__(256) void gemm3b(const float* __restrict__ x,
                                              const float* __restrict__ t_emb,
                                              const float* __restrict__ f_emb) {
  const int tid = threadIdx.x;
  const int wave = tid >> 6, lane = tid & 63;
  const int quad = (lane >> 4) & 3, n16 = lane & 15;
  const int rt = blockIdx.x / 10, ct = blockIdx.x % 10;
  const int rowb = rt * 128 + wave * 32;

  // per-lane row sources for the two 16-row groups
  const float* base0;  // row rowb+n16
  const float* base1;  // row rowb+16+n16
  const float* xrow;   // block-uniform additive part (rt<16 only)
  if (rt < 16) {
    base0 = t_emb + (size_t)(wave * 32 + n16) * D_;
    base1 = base0 + 16 * D_;
    xrow = x + (size_t)rt * D_;
  } else {
    base0 = f_emb + (size_t)(wave * 32 + n16) * D_;
    base1 = base0 + 16 * D_;
    xrow = nullptr;
  }

  f32x4 acc[2][4];
#pragma unroll
  for (int j = 0; j < 4; ++j) {
    acc[0][j] = (f32x4){0.f, 0.f, 0.f, 0.f};
    acc[1][j] = (f32x4){0.f, 0.f, 0.f, 0.f};
  }

#pragma unroll 4
  for (int kt = 0; kt < 24; ++kt) {
    const int term = kt >> 3;                  // 0:hi 1:lo 2:hi (A-side)
    const int kb = (kt & 7) * 32 + quad * 8;   // 8 consecutive k's
    float4 t0a = *(const float4*)(base0 + kb);
    float4 t0b = *(const float4*)(base0 + kb + 4);
    float4 t1a = *(const float4*)(base1 + kb);
    float4 t1b = *(const float4*)(base1 + kb + 4);
    if (rt < 16) {  // block-uniform branch
      const float4 xa = *(const float4*)(xrow + kb);
      const float4 xb = *(const float4*)(xrow + kb + 4);
      t0a.x += xa.x; t0a.y += xa.y; t0a.z += xa.z; t0a.w += xa.w;
      t0b.x += xb.x; t0b.y += xb.y; t0b.z += xb.z; t0b.w += xb.w;
      t1a.x += xa.x; t1a.y += xa.y; t1a.z += xa.z; t1a.w += xa.w;
      t1b.x += xb.x; t1b.y += xb.y; t1b.z += xb.z; t1b.w += xb.w;
    }
    const short8 av0 = mk_frag(t0a, t0b, term);
    const short8 av1 = mk_frag(t1a, t1b, term);
    const short8* bp = (const short8*)g_Bbuf + ((kt * 10 + ct) * 4) * 64 + lane;
#pragma unroll
    for (int jtl = 0; jtl < 4; ++jtl) {
      const short8 bf = bp[jtl * 64];
      acc[0][jtl] =
          __builtin_amdgcn_mfma_f32_16x16x32_bf16(av0, bf, acc[0][jtl], 0, 0, 0);
      acc[1][jtl] =
          __builtin_amdgcn_mfma_f32_16x16x32_bf16(av1, bf, acc[1][jtl], 0, 0, 0);
    }
  }

#pragma unroll
  for (int g = 0; g < 2; ++g)
#pragma unroll
    for (int jtl = 0; jtl < 4; ++jtl)
#pragma unroll
      for (int r = 0; r < 4; ++r) {
        const float val = acc[g][jtl][r];
        const int grow = rowb + g * 16 + quad * 4 + r;  // C/D: row=quad*4+reg
        const int col = ct * 64 + jtl * 16 + n16;        //      col=lane&15
        if (rt < 16) {
          if (ct < 8) g_U[grow * 512 + col] = val;
          else        g_C[grow * 128 + (col - 512)] = val;
        } else if (ct < 8) {
          g_Vt[col * 128 + (grow - 2048)] = val;  // transposed store (tiny)
        }
      }
}

// ---------------------------------------------------------------------------
// decode2 (proven): packed-f32 VALU pass. Block = 4 rows, 8 waves.
// Wave w owns e-slice [64w,64w+64); lane owns f-pair {2l,2l+1} as f32x2.
// pre = Ar*(U+V) + (Br*G + K) via v_pk_fma_f32; relu; fold W2; LDS reduce.
// ---------------------------------------------------------------------------
__global__ __launch_bounds__(512) void decode2(const float* __restrict__ b2,
                                               float* __restrict__ out) {
  __shared__ float part[8][64][17];  // 34.8KB partials
  const int tid = threadIdx.x;
  const int w = tid >> 6, lane = tid & 63;
  const int bnt0 = blockIdx.x * 4;

  const f32x2 sf2 = *(const f32x2*)(g_sf + 2 * lane);
  const f32x2 sqf2 = *(const f32x2*)(g_sqf + 2 * lane);
  f32x2 Ar[4], Br[4];
#pragma unroll
  for (int ti = 0; ti < 4; ++ti) {
    const float sx = g_sxt[bnt0 + ti];
    const float sqx = g_sqxt[bnt0 + ti];
    const f32x2 c2 = *(const f32x2*)(g_C + (bnt0 + ti) * 128 + 2 * lane);
    const f32x2 mu = (sf2 + sx) * (1.0f / 256.0f);
    const f32x2 var = (sqf2 + 2.0f * c2 + sqx) * (1.0f / 256.0f) - mu * mu;
    f32x2 rs;
    rs.x = rsqrtf(var.x + 1e-5f);
    rs.y = rsqrtf(var.y + 1e-5f);
    Ar[ti] = rs;
    Br[ti] = -rs * mu;
  }

  f32x2 o0[4] = {(f32x2){0.f, 0.f}, (f32x2){0.f, 0.f},
                 (f32x2){0.f, 0.f}, (f32x2){0.f, 0.f}};
  f32x2 o1[4] = {(f32x2){0.f, 0.f}, (f32x2){0.f, 0.f},
                 (f32x2){0.f, 0.f}, (f32x2){0.f, 0.f}};
  const int ebase = __builtin_amdgcn_readfirstlane(w * 64);
#pragma unroll 8
  for (int ei = 0; ei < 64; ++ei) {
    const int e = ebase + ei;
    const float4 gkw = *(const float4*)(g_GKW + 4 * e);           // s_load
    const f32x2 v2 = *(const f32x2*)(g_Vt + e * 128 + 2 * lane);  // coalesced
#pragma unroll
    for (int ti = 0; ti < 4; ++ti) {
      const float u = g_U[(bnt0 + ti) * 512 + e];  // wave-uniform s_load
      const f32x2 s = v2 + u;                                   // pk_add
      const f32x2 pre = Ar[ti] * s + (Br[ti] * gkw.x + gkw.y);  // pk_fma x2
      f32x2 y;
      y.x = fmaxf(pre.x, 0.f);
      y.y = fmaxf(pre.y, 0.f);
      o0[ti] += y * gkw.z;  // pk_fma
      o1[ti] += y * gkw.w;  // pk_fma
    }
  }

#pragma unroll
  for (int ti = 0; ti < 4; ++ti) {
    part[w][lane][ti * 4 + 0] = o0[ti].x;  // f even, ch0
    part[w][lane][ti * 4 + 1] = o1[ti].x;  // f even, ch1
    part[w][lane][ti * 4 + 2] = o0[ti].y;  // f odd,  ch0
    part[w][lane][ti * 4 + 3] = o1[ti].y;  // f odd,  ch1
  }
  __syncthreads();

  const int t = tid >> 7, f = tid & 127;
  const int m = f >> 1, ff = f & 1;
  float r0 = b2[0], r1 = b2[1];
#pragma unroll
  for (int w2 = 0; w2 < 8; ++w2) {
    r0 += part[w2][m][t * 4 + ff * 2 + 0];
    r1 += part[w2][m][t * 4 + ff * 2 + 1];
  }
  float2 res;
  res.x = r0;
  res.y = r1;
  *(float2*)(out + ((bnt0 + t) * 128 + f) * 2) = res;
}

// ---------------------------------------------------------------------------
extern "C" void kernel_launch(void* const* d_in, const int* in_sizes, int n_in,
                              void* d_out, int out_size, void* d_ws,
                              size_t ws_size, hipStream_t stream) {
  const float* x = (const float*)d_in[0];
  const float* t_emb = (const float*)d_in[1];
  const float* f_emb = (const float*)d_in[2];
  const float* ln_g = (const float*)d_in[3];
  const float* ln_b = (const float*)d_in[4];
  const float* W1 = (const float*)d_in[5];
  const float* b1 = (const float*)d_in[6];
  const float* W2 = (const float*)d_in[7];
  const float* b2 = (const float*)d_in[8];
  (void)d_ws; (void)ws_size;

  prep2<<<88, 256, 0, stream>>>(x, t_emb, f_emb, ln_g, ln_b, W1, b1, W2);
  gemm3b<<<170, 256, 0, stream>>>(x, t_emb, f_emb);
  decode2<<<512, 512, 0, stream>>>(b2, (float*)d_out);
}